// Round 9
// baseline (1426.472 us; speedup 1.0000x reference)
//
#include <hip/hip_runtime.h>
#include <math.h>

#define NROW 65536
#define NCOL 300
#define MDIM 9
#define NITER 5
#define BLOCK 256
#define WPB 4                     // waves per block
#define NBLOCKS_MAIN 2048         // 256 CU x 8 blocks/CU (VGPR<=64 => 8 waves/SIMD)
#define TOTAL_WAVES (NBLOCKS_MAIN * WPB)   // 8192 -> 8 rows/wave exactly

// ws float layout: [0,2700) = G (scratch); [2700,5400) = W' = (L^-1 G)/sqrt(factor);
//                  [5400,8100) = fA = factor * A
#define WS_W  (MDIM*NCOL)
#define WS_FA (2*MDIM*NCOL)

// DPP sum step: s += dpp_perm(s), invalid sources contribute 0 (old=0, bound_ctrl)
template<int CTRL>
__device__ __forceinline__ float dpp_fadd(float s) {
    int v = __builtin_amdgcn_update_dpp(0, __float_as_int(s), CTRL, 0xF, 0xF, true);
    return s + __int_as_float(v);
}
__device__ __forceinline__ float readlane_f(float v, int l) {
    return __int_as_float(__builtin_amdgcn_readlane(__float_as_int(v), l));
}
__device__ __forceinline__ float sgpr_f(float v) {
    return __int_as_float(__builtin_amdgcn_readfirstlane(__float_as_int(v)));
}

// ---------- precompute, stage 1 (grid-parallel): G = A * Cinv, fA = factor*A ----------
__global__ __launch_bounds__(256)
void ladmm_pre_g(const float* __restrict__ A,
                 const float* __restrict__ alphap,
                 const float* __restrict__ gammap,
                 float* __restrict__ ws)
{
    __shared__ float As[MDIM*NCOL];
    __shared__ float karr[NCOL];
    const int tid = threadIdx.x;
    const double al = (double)alphap[0];
    const double g  = (double)gammap[0];
    const double a    = al + 2.0*g;
    const double disc = sqrt(a*a - 4.0*g*g);
    const double r    = (2.0*g) / (a + disc);
    const double rn   = pow(r, (double)NCOL);
    const double factor = 1.0 / (g * (1.0/r - r) * (1.0 - rn));

    for (int d = tid; d < NCOL; d += 256) {
        int dd = (d < NCOL - d) ? d : NCOL - d;
        karr[d] = (float)(factor * (pow(r,(double)dd) + pow(r,(double)(NCOL-dd))));
    }
    for (int i = tid; i < MDIM*NCOL; i += 256) As[i] = A[i];
    __syncthreads();
    const int e = blockIdx.x * 256 + tid;
    if (e < MDIM*NCOL) {
        const int p = e / NCOL, j = e - p*NCOL;
        float s = 0.f;
        for (int k = 0; k < NCOL; ++k) {
            int d = j - k; if (d < 0) d += NCOL;
            s += As[p*NCOL+k] * karr[d];
        }
        ws[e] = s;
        ws[WS_FA + e] = (float)(factor * (double)As[e]);   // pre-scaled A for bA
    }
}

// ---------- precompute, stage 2: S = I + G A^T, Cholesky, W' = (L^-1 G)/sqrt(factor) ----------
__global__ __launch_bounds__(256)
void ladmm_pre_w(const float* __restrict__ A,
                 const float* __restrict__ alphap,
                 const float* __restrict__ gammap,
                 float* __restrict__ ws)
{
    __shared__ double Sd[MDIM*MDIM];
    __shared__ double Ld[MDIM*MDIM];
    const int tid = threadIdx.x;
    const double al = (double)alphap[0];
    const double g  = (double)gammap[0];
    const double a    = al + 2.0*g;
    const double disc = sqrt(a*a - 4.0*g*g);
    const double r    = (2.0*g) / (a + disc);
    const double rn   = pow(r, (double)NCOL);
    const double factor = 1.0 / (g * (1.0/r - r) * (1.0 - rn));
    const double isqf  = 1.0 / sqrt(factor);

    // S = I9 + G A^T  (SPD)
    if (tid < MDIM*MDIM) {
        int p = tid / MDIM, q = tid - p*MDIM;
        double s = (p == q) ? 1.0 : 0.0;
        for (int j = 0; j < NCOL; ++j)
            s += (double)ws[p*NCOL+j] * (double)A[q*NCOL+j];
        Sd[tid] = s;
    }
    __syncthreads();
    if (tid == 0) {
        // Cholesky S = L L^T (double, 9x9)
        double L[MDIM][MDIM];
        for (int i = 0; i < MDIM; ++i)
            for (int j = 0; j <= i; ++j) {
                double s = Sd[i*MDIM+j];
                for (int m = 0; m < j; ++m) s -= L[i][m]*L[j][m];
                L[i][j] = (i == j) ? sqrt(s) : s / L[j][j];
            }
        for (int i = 0; i < MDIM; ++i)
            for (int j = 0; j <= i; ++j) Ld[i*MDIM+j] = L[i][j];
    }
    __syncthreads();
    // W' = (L^-1 G)/sqrt(factor): with rs = factor*rsd, corr = W'^T (W' rs) = Woodbury exactly
    for (int j = tid; j < NCOL; j += 256) {
        double wcol[MDIM];
        for (int p = 0; p < MDIM; ++p) {
            double s = (double)ws[p*NCOL + j];
            for (int k = 0; k < p; ++k) s -= Ld[p*MDIM+k] * wcol[k];
            wcol[p] = s / Ld[p*MDIM+p];
            ws[WS_W + p*NCOL + j] = (float)(wcol[p] * isqf);
        }
    }
}

// ---------- main: W in LDS (row-major, stride-5 lanes -> conflict-free), VGPR<=64 ----------
__global__ __launch_bounds__(BLOCK, 8)
void ladmm_main(const float* __restrict__ b,
                const float* __restrict__ x0,
                const float* __restrict__ alphap,
                const float* __restrict__ gammap,
                const float* __restrict__ lamp,
                const float* __restrict__ ws,
                float* __restrict__ out)
{
    __shared__ float Ws[MDIM*NCOL];   // 10.8 KB; gcd(5,32)=1 -> bank-conflict-free reads

    const int tid  = threadIdx.x;
    const int lane = tid & 63;
    const int wv   = tid >> 6;

    const float al  = alphap[0];
    const float g   = gammap[0];
    const float lam = lamp[0];
    const float thr = lam / g;

    // geometric-kernel constants (uniform -> SGPR)
    const float aa   = al + 2.f*g;
    const float disc = sqrtf(aa*aa - 4.f*g*g);
    const float r    = sgpr_f((2.f*g) / (aa + disc));
    const float q    = sgpr_f(r*r*r*r*r);
    const float invq = sgpr_f(1.f / q);
    const float rn   = powf(r, (float)NCOL);
    const float factor = sgpr_f(1.f / (g * (1.f/r - r) * (1.f - rn)));
    const float fal  = sgpr_f(factor * al);
    const float fg   = sgpr_f(factor * g);
    const float r2 = sgpr_f(r*r), r3 = sgpr_f(r*r*r), r4 = sgpr_f(r*r*r*r);

    const bool act = (lane < 60);
    const int  j0  = lane * 5;
    const int  jl  = act ? j0 : 0;            // clamped for LDS addressing
    const int  lprev = (lane == 0) ? 59 : lane - 1;

    // gated Hillis-Steele weights (window 8 lanes; q^8 = 2^-40 -> exact enough)
    const float q2 = q*q, q4 = q2*q2;
    const float wf1 = (lane>=1)?q:0.f, wf2=(lane>=2)?q2:0.f, wf4=(lane>=4)?q4:0.f;
    const float wb1 = (lane<=62)?q:0.f, wb2=(lane<=61)?q2:0.f, wb4=(lane<=59)?q4:0.f;
    const float vwF = powf(r, (float)(j0 + 1));
    const float vwB = act ? powf(r, (float)(296 - j0)) : 0.f;

    // stage W' into LDS once (all waves), then waves run independently
    for (int i = tid; i < MDIM*NCOL; i += BLOCK) Ws[i] = ws[WS_W + i];
    __syncthreads();

    const float* __restrict__ fA = ws + WS_FA;

    const int gwave = blockIdx.x * WPB + wv;
    for (int row = gwave; row < NROW; row += TOTAL_WAVES) {
        float xc[5];
        {
            const float* xr = x0 + (size_t)row * NCOL + j0;
            #pragma unroll
            for (int i = 0; i < 5; ++i) xc[i] = act ? xr[i] : 0.f;
        }
        float xm = __shfl(xc[4], lprev);

        // bA pre-scaled by factor (fA = factor*A)
        float bA[5] = {0.f,0.f,0.f,0.f,0.f};
        {
            const float* brow = b + (size_t)row * MDIM;
            #pragma unroll
            for (int p = 0; p < MDIM; ++p) {
                float bv = brow[p];
                if (act) {
                    #pragma unroll
                    for (int i = 0; i < 5; ++i)
                        bA[i] += bv * fA[p*NCOL + j0 + i];
                }
            }
        }
        // collapsed dual state: eh = c - dx (TV), th = min(pre,0) - x (nonneg)
        float eh[5], th[5];
        #pragma unroll
        for (int i = 0; i < 5; ++i) {
            float xjm1 = (i == 0) ? xm : xc[i-1];
            eh[i] = xc[i] - xjm1;
            th[i] = -xc[i];
        }

        #pragma unroll
        for (int it = 0; it < NITER; ++it) {
            float rs[5];
            if (act) {
                #pragma unroll
                for (int i = 0; i < 5; ++i) {
                    float xjm1 = (i == 0) ? xm : xc[i-1];
                    float xj = xc[i];
                    float dx  = xjm1 - xj;
                    float v   = fmaf(2.f, dx, eh[i]);
                    float c   = fminf(fmaxf(v, -thr), thr);     // v_med3
                    eh[i] = c - dx;
                    float pre = fmaf(2.f, xj, th[i]);
                    float mn  = fminf(pre, 0.f);
                    th[i] = mn - xj;
                    rs[i] = fmaf(-fal, th[i], fmaf(-fg, eh[i], bA[i]));
                }
            } else {
                #pragma unroll
                for (int i = 0; i < 5; ++i) rs[i] = 0.f;
            }

            // ---- rs @ Cinv_raw via two geometric scans ----
            float l0 = rs[0];
            float l1 = fmaf(r, l0, rs[1]);
            float l2 = fmaf(r, l1, rs[2]);
            float l3 = fmaf(r, l2, rs[3]);
            float l4 = fmaf(r, l3, rs[4]);
            float S = l4, P = S;
            P = fmaf(wf1, __shfl_up(P, 1), P);
            P = fmaf(wf2, __shfl_up(P, 2), P);
            P = fmaf(wf4, __shfl_up(P, 4), P);
            float E    = (P - S) * invq;
            float Ltot = readlane_f(P, 59);
            float m4 = rs[4];
            float m3 = fmaf(r, m4, rs[3]);
            float m2 = fmaf(r, m3, rs[2]);
            float m1 = fmaf(r, m2, rs[1]);
            float m0 = fmaf(r, m1, rs[0]);
            float T = m0, Qs = T;
            Qs = fmaf(wb1, __shfl_down(Qs, 1), Qs);
            Qs = fmaf(wb2, __shfl_down(Qs, 2), Qs);
            Qs = fmaf(wb4, __shfl_down(Qs, 4), Qs);
            float Ep   = (Qs - T) * invq;
            float Atot = readlane_f(Qs, 0);

            // y[i] = (l_i + m_i - rs_i) + r^i*D1 + r^(4-i)*D2
            float D1 = fmaf(r, E,  vwF * Ltot);
            float D2 = fmaf(r, Ep, vwB * Atot);
            float y[5];
            y[0] = (l0 + m0 - rs[0]) + D1;        y[0] = fmaf(r4, D2, y[0]);
            y[1] = (l1 + m1 - rs[1]);             y[1] = fmaf(r,  D1, y[1]); y[1] = fmaf(r3, D2, y[1]);
            y[2] = (l2 + m2 - rs[2]);             y[2] = fmaf(r2, D1, y[2]); y[2] = fmaf(r2, D2, y[2]);
            y[3] = (l3 + m3 - rs[3]);             y[3] = fmaf(r3, D1, y[3]); y[3] = fmaf(r,  D2, y[3]);
            y[4] = (l4 + m4 - rs[4]) + D2;        y[4] = fmaf(r4, D1, y[4]);

            // ---- rank-9: project W' (LDS), DPP all-reduce, correct W' ----
            #pragma unroll
            for (int p = 0; p < MDIM; ++p) {
                const float* wp = &Ws[p*NCOL + jl];
                float w0 = wp[0], w1 = wp[1], w2 = wp[2], w3 = wp[3], w4 = wp[4];
                float s =       rs[0] * w0;
                s = fmaf(rs[1], w1, s);
                s = fmaf(rs[2], w2, s);
                s = fmaf(rs[3], w3, s);
                s = fmaf(rs[4], w4, s);
                s = dpp_fadd<0x111>(s);   // row_shr:1
                s = dpp_fadd<0x112>(s);   // row_shr:2
                s = dpp_fadd<0x114>(s);   // row_shr:4
                s = dpp_fadd<0x118>(s);   // row_shr:8
                s = dpp_fadd<0x142>(s);   // row_bcast15
                s = dpp_fadd<0x143>(s);   // row_bcast31 -> lane 63 has full sum
                float tp = readlane_f(s, 63);      // SGPR broadcast
                y[0] = fmaf(-tp, w0, y[0]);
                y[1] = fmaf(-tp, w1, y[1]);
                y[2] = fmaf(-tp, w2, y[2]);
                y[3] = fmaf(-tp, w3, y[3]);
                y[4] = fmaf(-tp, w4, y[4]);
            }

            xm = __shfl(y[4], lprev);
            #pragma unroll
            for (int i = 0; i < 5; ++i) xc[i] = y[i];
        }

        if (act) {
            float* orow = out + (size_t)row * NCOL + j0;
            #pragma unroll
            for (int i = 0; i < 5; ++i) orow[i] = xc[i];
        }
    }
}

extern "C" void kernel_launch(void* const* d_in, const int* in_sizes, int n_in,
                              void* d_out, int out_size, void* d_ws, size_t ws_size,
                              hipStream_t stream) {
    const float* b     = (const float*)d_in[0];
    // d_in[1] = target (unused, shape only)
    const float* x0    = (const float*)d_in[2];
    const float* A     = (const float*)d_in[3];
    const float* alpha = (const float*)d_in[4];
    const float* gamma = (const float*)d_in[5];
    const float* lam   = (const float*)d_in[6];
    float* out = (float*)d_out;
    float* ws  = (float*)d_ws;

    ladmm_pre_g<<<dim3((MDIM*NCOL + 255)/256), dim3(256), 0, stream>>>(A, alpha, gamma, ws);
    ladmm_pre_w<<<dim3(1), dim3(256), 0, stream>>>(A, alpha, gamma, ws);
    ladmm_main<<<dim3(NBLOCKS_MAIN), dim3(BLOCK), 0, stream>>>(b, x0, alpha, gamma, lam, ws, out);
}

// Round 10
// 193.392 us; speedup vs baseline: 7.3761x; 7.3761x over previous
//
#include <hip/hip_runtime.h>
#include <math.h>

#define NROW 65536
#define NCOL 300
#define MDIM 9
#define NITER 5
#define BLOCK 256
#define WPB 4                     // waves per block
#define NBLOCKS_MAIN 2048         // grid-stride rows; 8 rows/wave if fully resident
#define TOTAL_WAVES (NBLOCKS_MAIN * WPB)   // 8192

// ws float layout: [0,2700) = G (scratch); [2700,5400) = W' = (L^-1 G)/sqrt(factor);
//                  [5400,8100) = fA = factor * A
#define WS_W  (MDIM*NCOL)
#define WS_FA (2*MDIM*NCOL)

// DPP sum step: s += dpp_perm(s), invalid sources contribute 0 (old=0, bound_ctrl)
template<int CTRL>
__device__ __forceinline__ float dpp_fadd(float s) {
    int v = __builtin_amdgcn_update_dpp(0, __float_as_int(s), CTRL, 0xF, 0xF, true);
    return s + __int_as_float(v);
}
__device__ __forceinline__ float readlane_f(float v, int l) {
    return __int_as_float(__builtin_amdgcn_readlane(__float_as_int(v), l));
}
__device__ __forceinline__ float sgpr_f(float v) {
    return __int_as_float(__builtin_amdgcn_readfirstlane(__float_as_int(v)));
}

// ---------- precompute, stage 1 (grid-parallel): G = A * Cinv, fA = factor*A ----------
__global__ __launch_bounds__(256)
void ladmm_pre_g(const float* __restrict__ A,
                 const float* __restrict__ alphap,
                 const float* __restrict__ gammap,
                 float* __restrict__ ws)
{
    __shared__ float As[MDIM*NCOL];
    __shared__ float karr[NCOL];
    const int tid = threadIdx.x;
    const double al = (double)alphap[0];
    const double g  = (double)gammap[0];
    const double a    = al + 2.0*g;
    const double disc = sqrt(a*a - 4.0*g*g);
    const double r    = (2.0*g) / (a + disc);
    const double rn   = pow(r, (double)NCOL);
    const double factor = 1.0 / (g * (1.0/r - r) * (1.0 - rn));

    for (int d = tid; d < NCOL; d += 256) {
        int dd = (d < NCOL - d) ? d : NCOL - d;
        karr[d] = (float)(factor * (pow(r,(double)dd) + pow(r,(double)(NCOL-dd))));
    }
    for (int i = tid; i < MDIM*NCOL; i += 256) As[i] = A[i];
    __syncthreads();
    const int e = blockIdx.x * 256 + tid;
    if (e < MDIM*NCOL) {
        const int p = e / NCOL, j = e - p*NCOL;
        float s = 0.f;
        for (int k = 0; k < NCOL; ++k) {
            int d = j - k; if (d < 0) d += NCOL;
            s += As[p*NCOL+k] * karr[d];
        }
        ws[e] = s;
        ws[WS_FA + e] = (float)(factor * (double)As[e]);   // pre-scaled A for bA
    }
}

// ---------- precompute, stage 2: S = I + G A^T, Cholesky, W' = (L^-1 G)/sqrt(factor) ----------
__global__ __launch_bounds__(256)
void ladmm_pre_w(const float* __restrict__ A,
                 const float* __restrict__ alphap,
                 const float* __restrict__ gammap,
                 float* __restrict__ ws)
{
    __shared__ double Sd[MDIM*MDIM];
    __shared__ double Ld[MDIM*MDIM];
    const int tid = threadIdx.x;
    const double al = (double)alphap[0];
    const double g  = (double)gammap[0];
    const double a    = al + 2.0*g;
    const double disc = sqrt(a*a - 4.0*g*g);
    const double r    = (2.0*g) / (a + disc);
    const double rn   = pow(r, (double)NCOL);
    const double factor = 1.0 / (g * (1.0/r - r) * (1.0 - rn));
    const double isqf  = 1.0 / sqrt(factor);

    // S = I9 + G A^T  (SPD)
    if (tid < MDIM*MDIM) {
        int p = tid / MDIM, q = tid - p*MDIM;
        double s = (p == q) ? 1.0 : 0.0;
        for (int j = 0; j < NCOL; ++j)
            s += (double)ws[p*NCOL+j] * (double)A[q*NCOL+j];
        Sd[tid] = s;
    }
    __syncthreads();
    if (tid == 0) {
        // Cholesky S = L L^T (double, 9x9)
        double L[MDIM][MDIM];
        for (int i = 0; i < MDIM; ++i)
            for (int j = 0; j <= i; ++j) {
                double s = Sd[i*MDIM+j];
                for (int m = 0; m < j; ++m) s -= L[i][m]*L[j][m];
                L[i][j] = (i == j) ? sqrt(s) : s / L[j][j];
            }
        for (int i = 0; i < MDIM; ++i)
            for (int j = 0; j <= i; ++j) Ld[i*MDIM+j] = L[i][j];
    }
    __syncthreads();
    // W' = (L^-1 G)/sqrt(factor): with rs = factor*rsd, corr = W'^T (W' rs) = Woodbury exactly
    for (int j = tid; j < NCOL; j += 256) {
        double wcol[MDIM];
        for (int p = 0; p < MDIM; ++p) {
            double s = (double)ws[p*NCOL + j];
            for (int k = 0; k < p; ++k) s -= Ld[p*MDIM+k] * wcol[k];
            wcol[p] = s / Ld[p*MDIM+p];
            ws[WS_W + p*NCOL + j] = (float)(wcol[p] * isqf);
        }
    }
}

// ---------- main (no LDS; W in registers; butterfly reduce; window-4 scans) ----------
__global__ __launch_bounds__(BLOCK)
void ladmm_main(const float* __restrict__ b,
                const float* __restrict__ x0,
                const float* __restrict__ alphap,
                const float* __restrict__ gammap,
                const float* __restrict__ lamp,
                const float* __restrict__ ws,
                float* __restrict__ out)
{
    const int tid  = threadIdx.x;
    const int lane = tid & 63;
    const int wv   = tid >> 6;

    const float al  = alphap[0];
    const float g   = gammap[0];
    const float lam = lamp[0];
    const float thr = lam / g;

    // geometric-kernel constants (uniform -> SGPR)
    const float aa   = al + 2.f*g;
    const float disc = sqrtf(aa*aa - 4.f*g*g);
    const float r    = sgpr_f((2.f*g) / (aa + disc));
    const float q    = sgpr_f(r*r*r*r*r);
    const float invq = sgpr_f(1.f / q);
    const float rn   = powf(r, (float)NCOL);
    const float factor = sgpr_f(1.f / (g * (1.f/r - r) * (1.f - rn)));
    const float fal  = sgpr_f(factor * al);
    const float fg   = sgpr_f(factor * g);
    const float r2 = sgpr_f(r*r), r3 = sgpr_f(r*r*r), r4 = sgpr_f(r*r*r*r);

    const bool act = (lane < 60);
    const int  j0  = lane * 5;
    const int  lprev = (lane == 0) ? 59 : lane - 1;

    // gated Hillis-Steele weights, window 4 (q^4 = 2^-20 truncation ~1e-5: safe)
    const float q2 = q*q;
    const float wf1 = (lane>=1)?q:0.f, wf2=(lane>=2)?q2:0.f;
    const float wb1 = (lane<=62)?q:0.f, wb2=(lane<=61)?q2:0.f;
    const float vwF = powf(r, (float)(j0 + 1));
    const float vwB = act ? powf(r, (float)(296 - j0)) : 0.f;

    // W' table in registers (45 VGPR); no LDS anywhere
    float Wreg[MDIM][5];
    #pragma unroll
    for (int p = 0; p < MDIM; ++p) {
        #pragma unroll
        for (int i = 0; i < 5; ++i)
            Wreg[p][i] = act ? ws[WS_W + p*NCOL + j0 + i] : 0.f;
    }
    const float* __restrict__ fA = ws + WS_FA;

    const int gwave = blockIdx.x * WPB + wv;
    for (int row = gwave; row < NROW; row += TOTAL_WAVES) {
        float xc[5];
        {
            const float* xr = x0 + (size_t)row * NCOL + j0;
            #pragma unroll
            for (int i = 0; i < 5; ++i) xc[i] = act ? xr[i] : 0.f;
        }
        float xm = __shfl(xc[4], lprev);

        // bA pre-scaled by factor (fA = factor*A)
        float bA[5] = {0.f,0.f,0.f,0.f,0.f};
        {
            const float* brow = b + (size_t)row * MDIM;
            #pragma unroll
            for (int p = 0; p < MDIM; ++p) {
                float bv = brow[p];
                if (act) {
                    #pragma unroll
                    for (int i = 0; i < 5; ++i)
                        bA[i] += bv * fA[p*NCOL + j0 + i];
                }
            }
        }
        // collapsed dual state: eh = c - dx (TV), th = min(pre,0) - x (nonneg)
        float eh[5], th[5];
        #pragma unroll
        for (int i = 0; i < 5; ++i) {
            float xjm1 = (i == 0) ? xm : xc[i-1];
            eh[i] = xc[i] - xjm1;
            th[i] = -xc[i];
        }

        #pragma unroll
        for (int it = 0; it < NITER; ++it) {
            float rs[5];
            if (act) {
                #pragma unroll
                for (int i = 0; i < 5; ++i) {
                    float xjm1 = (i == 0) ? xm : xc[i-1];
                    float xj = xc[i];
                    float dx  = xjm1 - xj;
                    float v   = fmaf(2.f, dx, eh[i]);
                    float c   = fminf(fmaxf(v, -thr), thr);     // v_med3
                    eh[i] = c - dx;
                    float pre = fmaf(2.f, xj, th[i]);
                    float mn  = fminf(pre, 0.f);
                    th[i] = mn - xj;
                    rs[i] = fmaf(-fal, th[i], fmaf(-fg, eh[i], bA[i]));
                }
            } else {
                #pragma unroll
                for (int i = 0; i < 5; ++i) rs[i] = 0.f;
            }

            // ---- rs @ Cinv_raw via two geometric scans (window-4 Hillis-Steele) ----
            float l0 = rs[0];
            float l1 = fmaf(r, l0, rs[1]);
            float l2 = fmaf(r, l1, rs[2]);
            float l3 = fmaf(r, l2, rs[3]);
            float l4 = fmaf(r, l3, rs[4]);
            float S = l4, P = S;
            P = fmaf(wf1, __shfl_up(P, 1), P);
            P = fmaf(wf2, __shfl_up(P, 2), P);
            float E    = (P - S) * invq;
            float Ltot = readlane_f(P, 59);
            float m4 = rs[4];
            float m3 = fmaf(r, m4, rs[3]);
            float m2 = fmaf(r, m3, rs[2]);
            float m1 = fmaf(r, m2, rs[1]);
            float m0 = fmaf(r, m1, rs[0]);
            float T = m0, Qs = T;
            Qs = fmaf(wb1, __shfl_down(Qs, 1), Qs);
            Qs = fmaf(wb2, __shfl_down(Qs, 2), Qs);
            float Ep   = (Qs - T) * invq;
            float Atot = readlane_f(Qs, 0);

            // y[i] = (l_i + m_i - rs_i) + r^i*D1 + r^(4-i)*D2
            float D1 = fmaf(r, E,  vwF * Ltot);
            float D2 = fmaf(r, Ep, vwB * Atot);
            float y[5];
            y[0] = (l0 + m0 - rs[0]) + D1;        y[0] = fmaf(r4, D2, y[0]);
            y[1] = (l1 + m1 - rs[1]);             y[1] = fmaf(r,  D1, y[1]); y[1] = fmaf(r3, D2, y[1]);
            y[2] = (l2 + m2 - rs[2]);             y[2] = fmaf(r2, D1, y[2]); y[2] = fmaf(r2, D2, y[2]);
            y[3] = (l3 + m3 - rs[3]);             y[3] = fmaf(r3, D1, y[3]); y[3] = fmaf(r,  D2, y[3]);
            y[4] = (l4 + m4 - rs[4]) + D2;        y[4] = fmaf(r4, D1, y[4]);

            // ---- rank-9: project W', butterfly all-reduce (4 DPP + 2 shfl_xor), correct W' ----
            #pragma unroll
            for (int p = 0; p < MDIM; ++p) {
                float s =       rs[0] * Wreg[p][0];
                s = fmaf(rs[1], Wreg[p][1], s);
                s = fmaf(rs[2], Wreg[p][2], s);
                s = fmaf(rs[3], Wreg[p][3], s);
                s = fmaf(rs[4], Wreg[p][4], s);
                s = dpp_fadd<0xB1>(s);    // quad_perm [1,0,3,2] : xor1
                s = dpp_fadd<0x4E>(s);    // quad_perm [2,3,0,1] : xor2
                s = dpp_fadd<0x141>(s);   // row_half_mirror     : 8-group sum
                s = dpp_fadd<0x140>(s);   // row_mirror          : 16-group sum
                s += __shfl_xor(s, 16);   // cross rows (LDS pipe)
                s += __shfl_xor(s, 32);   // cross halves (LDS pipe)
                const float tp = s;       // wave-uniform, in VGPR
                y[0] = fmaf(-tp, Wreg[p][0], y[0]);
                y[1] = fmaf(-tp, Wreg[p][1], y[1]);
                y[2] = fmaf(-tp, Wreg[p][2], y[2]);
                y[3] = fmaf(-tp, Wreg[p][3], y[3]);
                y[4] = fmaf(-tp, Wreg[p][4], y[4]);
            }

            xm = __shfl(y[4], lprev);
            #pragma unroll
            for (int i = 0; i < 5; ++i) xc[i] = y[i];
        }

        if (act) {
            float* orow = out + (size_t)row * NCOL + j0;
            #pragma unroll
            for (int i = 0; i < 5; ++i) orow[i] = xc[i];
        }
    }
}

extern "C" void kernel_launch(void* const* d_in, const int* in_sizes, int n_in,
                              void* d_out, int out_size, void* d_ws, size_t ws_size,
                              hipStream_t stream) {
    const float* b     = (const float*)d_in[0];
    // d_in[1] = target (unused, shape only)
    const float* x0    = (const float*)d_in[2];
    const float* A     = (const float*)d_in[3];
    const float* alpha = (const float*)d_in[4];
    const float* gamma = (const float*)d_in[5];
    const float* lam   = (const float*)d_in[6];
    float* out = (float*)d_out;
    float* ws  = (float*)d_ws;

    ladmm_pre_g<<<dim3((MDIM*NCOL + 255)/256), dim3(256), 0, stream>>>(A, alpha, gamma, ws);
    ladmm_pre_w<<<dim3(1), dim3(256), 0, stream>>>(A, alpha, gamma, ws);
    ladmm_main<<<dim3(NBLOCKS_MAIN), dim3(BLOCK), 0, stream>>>(b, x0, alpha, gamma, lam, ws, out);
}

// Round 12
// 186.636 us; speedup vs baseline: 7.6431x; 1.0362x over previous
//
#include <hip/hip_runtime.h>
#include <math.h>

#define NROW 65536
#define NCOL 300
#define MDIM 9
#define NITER 5
#define BLOCK 256
#define WPB 4                     // waves per block
#define NBLOCKS_MAIN 2048         // grid-stride rows; 8 rows/wave
#define TOTAL_WAVES (NBLOCKS_MAIN * WPB)   // 8192

// ws float layout: [0,2700) = G (scratch); [2700,5400) = W' = (L^-1 G)/sqrt(factor);
//                  [5400,8100) = fA = factor * A
#define WS_W  (MDIM*NCOL)
#define WS_FA (2*MDIM*NCOL)

// DPP sum step: s += dpp_perm(s), invalid sources contribute 0 (old=0, bound_ctrl)
template<int CTRL>
__device__ __forceinline__ float dpp_fadd(float s) {
    int v = __builtin_amdgcn_update_dpp(0, __float_as_int(s), CTRL, 0xF, 0xF, true);
    return s + __int_as_float(v);
}
// DPP permute returning shifted value (OOB lanes read 0)
template<int CTRL>
__device__ __forceinline__ float dpp_mov0(float s) {
    return __int_as_float(__builtin_amdgcn_update_dpp(0, __float_as_int(s), CTRL, 0xF, 0xF, true));
}
// Convention verified on HW by the row_shr reduce chain (rounds 8-10):
// "shr" moves data toward HIGHER lanes: lane i <- lane i-N.
#define DPP_WAVE_SHR1 0x138   // lane i <- lane i-1, lane 0  <- 0   (shfl_up equivalent)
#define DPP_WAVE_SHL1 0x130   // lane i <- lane i+1, lane 63 <- 0   (shfl_down equivalent)

__device__ __forceinline__ float readlane_f(float v, int l) {
    return __int_as_float(__builtin_amdgcn_readlane(__float_as_int(v), l));
}
__device__ __forceinline__ float sgpr_f(float v) {
    return __int_as_float(__builtin_amdgcn_readfirstlane(__float_as_int(v)));
}

// ---------- precompute, stage 1 (grid-parallel): G = A * Cinv, fA = factor*A ----------
__global__ __launch_bounds__(256)
void ladmm_pre_g(const float* __restrict__ A,
                 const float* __restrict__ alphap,
                 const float* __restrict__ gammap,
                 float* __restrict__ ws)
{
    __shared__ float As[MDIM*NCOL];
    __shared__ float karr[NCOL];
    const int tid = threadIdx.x;
    const double al = (double)alphap[0];
    const double g  = (double)gammap[0];
    const double a    = al + 2.0*g;
    const double disc = sqrt(a*a - 4.0*g*g);
    const double r    = (2.0*g) / (a + disc);
    const double rn   = pow(r, (double)NCOL);
    const double factor = 1.0 / (g * (1.0/r - r) * (1.0 - rn));

    for (int d = tid; d < NCOL; d += 256) {
        int dd = (d < NCOL - d) ? d : NCOL - d;
        karr[d] = (float)(factor * (pow(r,(double)dd) + pow(r,(double)(NCOL-dd))));
    }
    for (int i = tid; i < MDIM*NCOL; i += 256) As[i] = A[i];
    __syncthreads();
    const int e = blockIdx.x * 256 + tid;
    if (e < MDIM*NCOL) {
        const int p = e / NCOL, j = e - p*NCOL;
        float s = 0.f;
        for (int k = 0; k < NCOL; ++k) {
            int d = j - k; if (d < 0) d += NCOL;
            s += As[p*NCOL+k] * karr[d];
        }
        ws[e] = s;
        ws[WS_FA + e] = (float)(factor * (double)As[e]);   // pre-scaled A for bA
    }
}

// ---------- precompute, stage 2: S = I + G A^T, Cholesky, W' = (L^-1 G)/sqrt(factor) ----------
__global__ __launch_bounds__(256)
void ladmm_pre_w(const float* __restrict__ A,
                 const float* __restrict__ alphap,
                 const float* __restrict__ gammap,
                 float* __restrict__ ws)
{
    __shared__ double Sd[MDIM*MDIM];
    __shared__ double Ld[MDIM*MDIM];
    const int tid = threadIdx.x;
    const double al = (double)alphap[0];
    const double g  = (double)gammap[0];
    const double a    = al + 2.0*g;
    const double disc = sqrt(a*a - 4.0*g*g);
    const double r    = (2.0*g) / (a + disc);
    const double rn   = pow(r, (double)NCOL);
    const double factor = 1.0 / (g * (1.0/r - r) * (1.0 - rn));
    const double isqf  = 1.0 / sqrt(factor);

    // S = I9 + G A^T  (SPD)
    if (tid < MDIM*MDIM) {
        int p = tid / MDIM, q = tid - p*MDIM;
        double s = (p == q) ? 1.0 : 0.0;
        for (int j = 0; j < NCOL; ++j)
            s += (double)ws[p*NCOL+j] * (double)A[q*NCOL+j];
        Sd[tid] = s;
    }
    __syncthreads();
    if (tid == 0) {
        // Cholesky S = L L^T (double, 9x9)
        double L[MDIM][MDIM];
        for (int i = 0; i < MDIM; ++i)
            for (int j = 0; j <= i; ++j) {
                double s = Sd[i*MDIM+j];
                for (int m = 0; m < j; ++m) s -= L[i][m]*L[j][m];
                L[i][j] = (i == j) ? sqrt(s) : s / L[j][j];
            }
        for (int i = 0; i < MDIM; ++i)
            for (int j = 0; j <= i; ++j) Ld[i*MDIM+j] = L[i][j];
    }
    __syncthreads();
    // W' = (L^-1 G)/sqrt(factor): with rs = factor*rsd, corr = W'^T (W' rs) = Woodbury exactly
    for (int j = tid; j < NCOL; j += 256) {
        double wcol[MDIM];
        for (int p = 0; p < MDIM; ++p) {
            double s = (double)ws[p*NCOL + j];
            for (int k = 0; k < p; ++k) s -= Ld[p*MDIM+k] * wcol[k];
            wcol[p] = s / Ld[p*MDIM+p];
            ws[WS_W + p*NCOL + j] = (float)(wcol[p] * isqf);
        }
    }
}

// ---------- main: zero LDS-pipe ops in the hot loop (all cross-lane via DPP/readlane) ----------
__global__ __launch_bounds__(BLOCK)
void ladmm_main(const float* __restrict__ b,
                const float* __restrict__ x0,
                const float* __restrict__ alphap,
                const float* __restrict__ gammap,
                const float* __restrict__ lamp,
                const float* __restrict__ ws,
                float* __restrict__ out)
{
    const int tid  = threadIdx.x;
    const int lane = tid & 63;
    const int wv   = tid >> 6;

    const float al  = alphap[0];
    const float g   = gammap[0];
    const float lam = lamp[0];
    const float thr = lam / g;

    // geometric-kernel constants (uniform -> SGPR)
    const float aa   = al + 2.f*g;
    const float disc = sqrtf(aa*aa - 4.f*g*g);
    const float r    = sgpr_f((2.f*g) / (aa + disc));
    const float q    = sgpr_f(r*r*r*r*r);
    const float invq = sgpr_f(1.f / q);
    const float rn   = powf(r, (float)NCOL);
    const float factor = sgpr_f(1.f / (g * (1.f/r - r) * (1.f - rn)));
    const float fal  = sgpr_f(factor * al);
    const float fg   = sgpr_f(factor * g);
    const float r2 = sgpr_f(r*r), r3 = sgpr_f(r*r*r), r4 = sgpr_f(r*r*r*r);

    const bool act = (lane < 60);
    const int  j0  = lane * 5;
    const float vwF = powf(r, (float)(j0 + 1));
    const float vwB = act ? powf(r, (float)(296 - j0)) : 0.f;

    // W' table in registers (45 VGPR); no LDS anywhere
    float Wreg[MDIM][5];
    #pragma unroll
    for (int p = 0; p < MDIM; ++p) {
        #pragma unroll
        for (int i = 0; i < 5; ++i)
            Wreg[p][i] = act ? ws[WS_W + p*NCOL + j0 + i] : 0.f;
    }
    const float* __restrict__ fA = ws + WS_FA;

    const int gwave = blockIdx.x * WPB + wv;
    for (int row = gwave; row < NROW; row += TOTAL_WAVES) {
        float xc[5];
        {
            const float* xr = x0 + (size_t)row * NCOL + j0;
            #pragma unroll
            for (int i = 0; i < 5; ++i) xc[i] = act ? xr[i] : 0.f;
        }
        // circular left neighbor x[j0-1]: lane l <- l-1 via wave_SHR1; lane 0 <- lane 59
        float xm;
        {
            float t   = dpp_mov0<DPP_WAVE_SHR1>(xc[4]);
            float s59 = readlane_f(xc[4], 59);
            xm = (lane == 0) ? s59 : t;
        }

        // bA pre-scaled by factor (fA = factor*A)
        float bA[5] = {0.f,0.f,0.f,0.f,0.f};
        {
            const float* brow = b + (size_t)row * MDIM;
            #pragma unroll
            for (int p = 0; p < MDIM; ++p) {
                float bv = brow[p];
                if (act) {
                    #pragma unroll
                    for (int i = 0; i < 5; ++i)
                        bA[i] += bv * fA[p*NCOL + j0 + i];
                }
            }
        }
        // collapsed dual state: eh = c - dx (TV), th = min(pre,0) - x (nonneg)
        float eh[5], th[5];
        #pragma unroll
        for (int i = 0; i < 5; ++i) {
            float xjm1 = (i == 0) ? xm : xc[i-1];
            eh[i] = xc[i] - xjm1;
            th[i] = -xc[i];
        }

        #pragma unroll
        for (int it = 0; it < NITER; ++it) {
            float rs[5];
            if (act) {
                #pragma unroll
                for (int i = 0; i < 5; ++i) {
                    float xjm1 = (i == 0) ? xm : xc[i-1];
                    float xj = xc[i];
                    float dx  = xjm1 - xj;
                    float v   = fmaf(2.f, dx, eh[i]);
                    float c   = fminf(fmaxf(v, -thr), thr);     // v_med3
                    eh[i] = c - dx;
                    float pre = fmaf(2.f, xj, th[i]);
                    float mn  = fminf(pre, 0.f);
                    th[i] = mn - xj;
                    rs[i] = fmaf(-fal, th[i], fmaf(-fg, eh[i], bA[i]));
                }
            } else {
                #pragma unroll
                for (int i = 0; i < 5; ++i) rs[i] = 0.f;
            }

            // ---- rs @ Cinv_raw via two geometric scans; cross-lane = wave-shift DPP ----
            float l0 = rs[0];
            float l1 = fmaf(r, l0, rs[1]);
            float l2 = fmaf(r, l1, rs[2]);
            float l3 = fmaf(r, l2, rs[3]);
            float l4 = fmaf(r, l3, rs[4]);
            float S = l4;
            // P_i = sum_{d=0..3} q^d S_{i-d}  (window-4, trunc q^4 = 2^-20)
            // needs lane i <- lane i-1  => wave_SHR1
            float P = S;
            P = fmaf(q, dpp_mov0<DPP_WAVE_SHR1>(P), S);
            P = fmaf(q, dpp_mov0<DPP_WAVE_SHR1>(P), S);
            P = fmaf(q, dpp_mov0<DPP_WAVE_SHR1>(P), S);
            float E    = (P - S) * invq;
            float Ltot = readlane_f(P, 59);

            float m4 = rs[4];
            float m3 = fmaf(r, m4, rs[3]);
            float m2 = fmaf(r, m3, rs[2]);
            float m1 = fmaf(r, m2, rs[1]);
            float m0 = fmaf(r, m1, rs[0]);
            float T = m0;
            // Q_i = sum_{d=0..3} q^d T_{i+d}  => lane i <- lane i+1 => wave_SHL1
            float Qs = T;
            Qs = fmaf(q, dpp_mov0<DPP_WAVE_SHL1>(Qs), T);
            Qs = fmaf(q, dpp_mov0<DPP_WAVE_SHL1>(Qs), T);
            Qs = fmaf(q, dpp_mov0<DPP_WAVE_SHL1>(Qs), T);
            float Ep   = (Qs - T) * invq;
            float Atot = readlane_f(Qs, 0);

            // y[i] = (l_i + m_i - rs_i) + r^i*D1 + r^(4-i)*D2
            float D1 = fmaf(r, E,  vwF * Ltot);
            float D2 = fmaf(r, Ep, vwB * Atot);
            float y[5];
            y[0] = (l0 + m0 - rs[0]) + D1;        y[0] = fmaf(r4, D2, y[0]);
            y[1] = (l1 + m1 - rs[1]);             y[1] = fmaf(r,  D1, y[1]); y[1] = fmaf(r3, D2, y[1]);
            y[2] = (l2 + m2 - rs[2]);             y[2] = fmaf(r2, D1, y[2]); y[2] = fmaf(r2, D2, y[2]);
            y[3] = (l3 + m3 - rs[3]);             y[3] = fmaf(r3, D1, y[3]); y[3] = fmaf(r,  D2, y[3]);
            y[4] = (l4 + m4 - rs[4]) + D2;        y[4] = fmaf(r4, D1, y[4]);

            // ---- rank-9: project W', all-VALU reduce (shr-chain + bcast, lane63 valid), correct W' ----
            #pragma unroll
            for (int p = 0; p < MDIM; ++p) {
                float s =       rs[0] * Wreg[p][0];
                s = fmaf(rs[1], Wreg[p][1], s);
                s = fmaf(rs[2], Wreg[p][2], s);
                s = fmaf(rs[3], Wreg[p][3], s);
                s = fmaf(rs[4], Wreg[p][4], s);
                s = dpp_fadd<0x111>(s);   // row_shr:1
                s = dpp_fadd<0x112>(s);   // row_shr:2
                s = dpp_fadd<0x114>(s);   // row_shr:4
                s = dpp_fadd<0x118>(s);   // row_shr:8  -> lane 15 of each row = row sum
                s = dpp_fadd<0x142>(s);   // row_bcast15
                s = dpp_fadd<0x143>(s);   // row_bcast31 -> lane 63 = full sum (HW-verified r8-r10)
                float tp = readlane_f(s, 63);      // SGPR
                y[0] = fmaf(-tp, Wreg[p][0], y[0]);
                y[1] = fmaf(-tp, Wreg[p][1], y[1]);
                y[2] = fmaf(-tp, Wreg[p][2], y[2]);
                y[3] = fmaf(-tp, Wreg[p][3], y[3]);
                y[4] = fmaf(-tp, Wreg[p][4], y[4]);
            }

            // circular neighbor for next iteration (VALU only)
            {
                float t   = dpp_mov0<DPP_WAVE_SHR1>(y[4]);
                float s59 = readlane_f(y[4], 59);
                xm = (lane == 0) ? s59 : t;
            }
            #pragma unroll
            for (int i = 0; i < 5; ++i) xc[i] = y[i];
        }

        if (act) {
            float* orow = out + (size_t)row * NCOL + j0;
            #pragma unroll
            for (int i = 0; i < 5; ++i) orow[i] = xc[i];
        }
    }
}

extern "C" void kernel_launch(void* const* d_in, const int* in_sizes, int n_in,
                              void* d_out, int out_size, void* d_ws, size_t ws_size,
                              hipStream_t stream) {
    const float* b     = (const float*)d_in[0];
    // d_in[1] = target (unused, shape only)
    const float* x0    = (const float*)d_in[2];
    const float* A     = (const float*)d_in[3];
    const float* alpha = (const float*)d_in[4];
    const float* gamma = (const float*)d_in[5];
    const float* lam   = (const float*)d_in[6];
    float* out = (float*)d_out;
    float* ws  = (float*)d_ws;

    ladmm_pre_g<<<dim3((MDIM*NCOL + 255)/256), dim3(256), 0, stream>>>(A, alpha, gamma, ws);
    ladmm_pre_w<<<dim3(1), dim3(256), 0, stream>>>(A, alpha, gamma, ws);
    ladmm_main<<<dim3(NBLOCKS_MAIN), dim3(BLOCK), 0, stream>>>(b, x0, alpha, gamma, lam, ws, out);
}

// Round 13
// 183.347 us; speedup vs baseline: 7.7802x; 1.0179x over previous
//
#include <hip/hip_runtime.h>
#include <math.h>

#define NROW 65536
#define NCOL 300
#define MDIM 9
#define NITER 5
#define BLOCK 256
#define WPB 4                     // waves per block
#define NBLOCKS_MAIN 2048         // grid-stride rows; 8 rows/wave
#define TOTAL_WAVES (NBLOCKS_MAIN * WPB)   // 8192

// ws float layout: [0,2700) = G (scratch); [2700,5400) = W' f32 (scratch);
//                  [5400,8100) = fA = factor*A; [8100,8100+1620) = W' packed bf16 [9][60][3]
#define WS_W  (MDIM*NCOL)
#define WS_FA (2*MDIM*NCOL)
#define WS_WP (3*MDIM*NCOL)       // 8100, as u32 words

// DPP sum step: s += dpp_perm(s), invalid sources contribute 0 (old=0, bound_ctrl)
template<int CTRL>
__device__ __forceinline__ float dpp_fadd(float s) {
    int v = __builtin_amdgcn_update_dpp(0, __float_as_int(s), CTRL, 0xF, 0xF, true);
    return s + __int_as_float(v);
}
// DPP permute returning shifted value (OOB lanes read 0)
template<int CTRL>
__device__ __forceinline__ float dpp_mov0(float s) {
    return __int_as_float(__builtin_amdgcn_update_dpp(0, __float_as_int(s), CTRL, 0xF, 0xF, true));
}
// HW-verified (r12): "shr" moves data toward HIGHER lanes: lane i <- lane i-N.
#define DPP_WAVE_SHR1 0x138   // lane i <- lane i-1, lane 0  <- 0
#define DPP_WAVE_SHL1 0x130   // lane i <- lane i+1, lane 63 <- 0

__device__ __forceinline__ float readlane_f(float v, int l) {
    return __int_as_float(__builtin_amdgcn_readlane(__float_as_int(v), l));
}
__device__ __forceinline__ float sgpr_f(float v) {
    return __int_as_float(__builtin_amdgcn_readfirstlane(__float_as_int(v)));
}
__device__ __forceinline__ unsigned bf16_rne(float f) {
    unsigned u = __float_as_uint(f);
    return (u + 0x7fffu + ((u >> 16) & 1u)) >> 16;
}

// ---------- precompute, stage 1 (grid-parallel): G = A * Cinv, fA = factor*A ----------
__global__ __launch_bounds__(256)
void ladmm_pre_g(const float* __restrict__ A,
                 const float* __restrict__ alphap,
                 const float* __restrict__ gammap,
                 float* __restrict__ ws)
{
    __shared__ float As[MDIM*NCOL];
    __shared__ float karr[NCOL];
    const int tid = threadIdx.x;
    const double al = (double)alphap[0];
    const double g  = (double)gammap[0];
    const double a    = al + 2.0*g;
    const double disc = sqrt(a*a - 4.0*g*g);
    const double r    = (2.0*g) / (a + disc);
    const double rn   = pow(r, (double)NCOL);
    const double factor = 1.0 / (g * (1.0/r - r) * (1.0 - rn));

    for (int d = tid; d < NCOL; d += 256) {
        int dd = (d < NCOL - d) ? d : NCOL - d;
        karr[d] = (float)(factor * (pow(r,(double)dd) + pow(r,(double)(NCOL-dd))));
    }
    for (int i = tid; i < MDIM*NCOL; i += 256) As[i] = A[i];
    __syncthreads();
    const int e = blockIdx.x * 256 + tid;
    if (e < MDIM*NCOL) {
        const int p = e / NCOL, j = e - p*NCOL;
        float s = 0.f;
        for (int k = 0; k < NCOL; ++k) {
            int d = j - k; if (d < 0) d += NCOL;
            s += As[p*NCOL+k] * karr[d];
        }
        ws[e] = s;
        ws[WS_FA + e] = (float)(factor * (double)As[e]);   // pre-scaled A for bA
    }
}

// ---------- precompute, stage 2: S = I + G A^T, Cholesky, W' = (L^-1 G)/sqrt(factor), pack ----------
__global__ __launch_bounds__(256)
void ladmm_pre_w(const float* __restrict__ A,
                 const float* __restrict__ alphap,
                 const float* __restrict__ gammap,
                 float* __restrict__ ws)
{
    __shared__ double Sd[MDIM*MDIM];
    __shared__ double Ld[MDIM*MDIM];
    const int tid = threadIdx.x;
    const double al = (double)alphap[0];
    const double g  = (double)gammap[0];
    const double a    = al + 2.0*g;
    const double disc = sqrt(a*a - 4.0*g*g);
    const double r    = (2.0*g) / (a + disc);
    const double rn   = pow(r, (double)NCOL);
    const double factor = 1.0 / (g * (1.0/r - r) * (1.0 - rn));
    const double isqf  = 1.0 / sqrt(factor);

    // S = I9 + G A^T  (SPD)
    if (tid < MDIM*MDIM) {
        int p = tid / MDIM, q = tid - p*MDIM;
        double s = (p == q) ? 1.0 : 0.0;
        for (int j = 0; j < NCOL; ++j)
            s += (double)ws[p*NCOL+j] * (double)A[q*NCOL+j];
        Sd[tid] = s;
    }
    __syncthreads();
    if (tid == 0) {
        // Cholesky S = L L^T (double, 9x9)
        double L[MDIM][MDIM];
        for (int i = 0; i < MDIM; ++i)
            for (int j = 0; j <= i; ++j) {
                double s = Sd[i*MDIM+j];
                for (int m = 0; m < j; ++m) s -= L[i][m]*L[j][m];
                L[i][j] = (i == j) ? sqrt(s) : s / L[j][j];
            }
        for (int i = 0; i < MDIM; ++i)
            for (int j = 0; j <= i; ++j) Ld[i*MDIM+j] = L[i][j];
    }
    __syncthreads();
    // W' = (L^-1 G)/sqrt(factor): with rs = factor*rsd, corr = W'^T (W' rs) = Woodbury exactly
    for (int j = tid; j < NCOL; j += 256) {
        double wcol[MDIM];
        for (int p = 0; p < MDIM; ++p) {
            double s = (double)ws[p*NCOL + j];
            for (int k = 0; k < p; ++k) s -= Ld[p*MDIM+k] * wcol[k];
            wcol[p] = s / Ld[p*MDIM+p];
            ws[WS_W + p*NCOL + j] = (float)(wcol[p] * isqf);
        }
    }
    __syncthreads();
    // pack per-lane slices: [p][lane][3] = {bf16(w1)<<16|bf16(w0), bf16(w3)<<16|bf16(w2), f32(w4)}
    unsigned* wp = (unsigned*)ws + WS_WP;
    for (int e = tid; e < MDIM*60; e += 256) {
        const int p = e / 60, l = e - p*60;
        const float* src = &ws[WS_W + p*NCOL + l*5];
        unsigned pk01 = (bf16_rne(src[1]) << 16) | bf16_rne(src[0]);
        unsigned pk23 = (bf16_rne(src[3]) << 16) | bf16_rne(src[2]);
        wp[e*3 + 0] = pk01;
        wp[e*3 + 1] = pk23;
        wp[e*3 + 2] = __float_as_uint(src[4]);
    }
}

// ---------- main: bf16-packed W table (27 regs) -> more waves/SIMD; all-DPP cross-lane ----------
__global__ __launch_bounds__(BLOCK)
void ladmm_main(const float* __restrict__ b,
                const float* __restrict__ x0,
                const float* __restrict__ alphap,
                const float* __restrict__ gammap,
                const float* __restrict__ lamp,
                const float* __restrict__ ws,
                float* __restrict__ out)
{
    const int tid  = threadIdx.x;
    const int lane = tid & 63;
    const int wv   = tid >> 6;

    const float al  = alphap[0];
    const float g   = gammap[0];
    const float lam = lamp[0];
    const float thr = lam / g;

    // geometric-kernel constants (uniform -> SGPR)
    const float aa   = al + 2.f*g;
    const float disc = sqrtf(aa*aa - 4.f*g*g);
    const float r    = sgpr_f((2.f*g) / (aa + disc));
    const float q    = sgpr_f(r*r*r*r*r);
    const float invq = sgpr_f(1.f / q);
    const float rn   = powf(r, (float)NCOL);
    const float factor = sgpr_f(1.f / (g * (1.f/r - r) * (1.f - rn)));
    const float fal  = sgpr_f(factor * al);
    const float fg   = sgpr_f(factor * g);
    const float r2 = sgpr_f(r*r), r3 = sgpr_f(r*r*r), r4 = sgpr_f(r*r*r*r);

    const bool act = (lane < 60);
    const int  j0  = lane * 5;
    const float vwF = powf(r, (float)(j0 + 1));
    const float vwB = act ? powf(r, (float)(296 - j0)) : 0.f;

    // W' table, bf16-packed: 27 VGPRs instead of 45
    unsigned Wpk[MDIM][3];
    {
        const unsigned* wp = (const unsigned*)ws + WS_WP;
        const int ll = act ? lane : 0;
        #pragma unroll
        for (int p = 0; p < MDIM; ++p) {
            #pragma unroll
            for (int k = 0; k < 3; ++k)
                Wpk[p][k] = act ? wp[(p*60 + ll)*3 + k] : 0u;
        }
    }
    const float* __restrict__ fA = ws + WS_FA;

    const int gwave = blockIdx.x * WPB + wv;
    for (int row = gwave; row < NROW; row += TOTAL_WAVES) {
        float xc[5];
        {
            const float* xr = x0 + (size_t)row * NCOL + j0;
            #pragma unroll
            for (int i = 0; i < 5; ++i) xc[i] = act ? xr[i] : 0.f;
        }
        // circular left neighbor x[j0-1]
        float xm;
        {
            float t   = dpp_mov0<DPP_WAVE_SHR1>(xc[4]);
            float s59 = readlane_f(xc[4], 59);
            xm = (lane == 0) ? s59 : t;
        }

        // bA pre-scaled by factor (fA = factor*A)
        float bA[5] = {0.f,0.f,0.f,0.f,0.f};
        {
            const float* brow = b + (size_t)row * MDIM;
            #pragma unroll
            for (int p = 0; p < MDIM; ++p) {
                float bv = brow[p];
                if (act) {
                    #pragma unroll
                    for (int i = 0; i < 5; ++i)
                        bA[i] += bv * fA[p*NCOL + j0 + i];
                }
            }
        }
        // collapsed dual state: eh = c - dx (TV), th = min(pre,0) - x (nonneg)
        float eh[5], th[5];
        #pragma unroll
        for (int i = 0; i < 5; ++i) {
            float xjm1 = (i == 0) ? xm : xc[i-1];
            eh[i] = xc[i] - xjm1;
            th[i] = -xc[i];
        }

        #pragma unroll
        for (int it = 0; it < NITER; ++it) {
            float rs[5];
            if (act) {
                #pragma unroll
                for (int i = 0; i < 5; ++i) {
                    float xjm1 = (i == 0) ? xm : xc[i-1];
                    float xj = xc[i];
                    float dx  = xjm1 - xj;
                    float v   = fmaf(2.f, dx, eh[i]);
                    float c   = fminf(fmaxf(v, -thr), thr);     // v_med3
                    eh[i] = c - dx;
                    float pre = fmaf(2.f, xj, th[i]);
                    float mn  = fminf(pre, 0.f);
                    th[i] = mn - xj;
                    rs[i] = fmaf(-fal, th[i], fmaf(-fg, eh[i], bA[i]));
                }
            } else {
                #pragma unroll
                for (int i = 0; i < 5; ++i) rs[i] = 0.f;
            }

            // ---- rs @ Cinv_raw via two geometric scans; cross-lane = wave-shift DPP ----
            float l0 = rs[0];
            float l1 = fmaf(r, l0, rs[1]);
            float l2 = fmaf(r, l1, rs[2]);
            float l3 = fmaf(r, l2, rs[3]);
            float l4 = fmaf(r, l3, rs[4]);
            float S = l4;
            float P = S;
            P = fmaf(q, dpp_mov0<DPP_WAVE_SHR1>(P), S);
            P = fmaf(q, dpp_mov0<DPP_WAVE_SHR1>(P), S);
            P = fmaf(q, dpp_mov0<DPP_WAVE_SHR1>(P), S);
            float E    = (P - S) * invq;
            float Ltot = readlane_f(P, 59);

            float m4 = rs[4];
            float m3 = fmaf(r, m4, rs[3]);
            float m2 = fmaf(r, m3, rs[2]);
            float m1 = fmaf(r, m2, rs[1]);
            float m0 = fmaf(r, m1, rs[0]);
            float T = m0;
            float Qs = T;
            Qs = fmaf(q, dpp_mov0<DPP_WAVE_SHL1>(Qs), T);
            Qs = fmaf(q, dpp_mov0<DPP_WAVE_SHL1>(Qs), T);
            Qs = fmaf(q, dpp_mov0<DPP_WAVE_SHL1>(Qs), T);
            float Ep   = (Qs - T) * invq;
            float Atot = readlane_f(Qs, 0);

            // y[i] = (l_i + m_i - rs_i) + r^i*D1 + r^(4-i)*D2
            float D1 = fmaf(r, E,  vwF * Ltot);
            float D2 = fmaf(r, Ep, vwB * Atot);
            float y[5];
            y[0] = (l0 + m0 - rs[0]) + D1;        y[0] = fmaf(r4, D2, y[0]);
            y[1] = (l1 + m1 - rs[1]);             y[1] = fmaf(r,  D1, y[1]); y[1] = fmaf(r3, D2, y[1]);
            y[2] = (l2 + m2 - rs[2]);             y[2] = fmaf(r2, D1, y[2]); y[2] = fmaf(r2, D2, y[2]);
            y[3] = (l3 + m3 - rs[3]);             y[3] = fmaf(r3, D1, y[3]); y[3] = fmaf(r,  D2, y[3]);
            y[4] = (l4 + m4 - rs[4]) + D2;        y[4] = fmaf(r4, D1, y[4]);

            // ---- rank-9: unpack bf16 W', project, all-VALU reduce, correct ----
            #pragma unroll
            for (int p = 0; p < MDIM; ++p) {
                const unsigned pk01 = Wpk[p][0], pk23 = Wpk[p][1];
                const float w0 = __uint_as_float(pk01 << 16);
                const float w1 = __uint_as_float(pk01 & 0xffff0000u);
                const float w2 = __uint_as_float(pk23 << 16);
                const float w3 = __uint_as_float(pk23 & 0xffff0000u);
                const float w4 = __uint_as_float(Wpk[p][2]);
                float s =       rs[0] * w0;
                s = fmaf(rs[1], w1, s);
                s = fmaf(rs[2], w2, s);
                s = fmaf(rs[3], w3, s);
                s = fmaf(rs[4], w4, s);
                s = dpp_fadd<0x111>(s);   // row_shr:1
                s = dpp_fadd<0x112>(s);   // row_shr:2
                s = dpp_fadd<0x114>(s);   // row_shr:4
                s = dpp_fadd<0x118>(s);   // row_shr:8
                s = dpp_fadd<0x142>(s);   // row_bcast15
                s = dpp_fadd<0x143>(s);   // row_bcast31 -> lane 63 = full sum
                float tp = readlane_f(s, 63);      // SGPR
                y[0] = fmaf(-tp, w0, y[0]);
                y[1] = fmaf(-tp, w1, y[1]);
                y[2] = fmaf(-tp, w2, y[2]);
                y[3] = fmaf(-tp, w3, y[3]);
                y[4] = fmaf(-tp, w4, y[4]);
            }

            // circular neighbor for next iteration (VALU only)
            {
                float t   = dpp_mov0<DPP_WAVE_SHR1>(y[4]);
                float s59 = readlane_f(y[4], 59);
                xm = (lane == 0) ? s59 : t;
            }
            #pragma unroll
            for (int i = 0; i < 5; ++i) xc[i] = y[i];
        }

        if (act) {
            float* orow = out + (size_t)row * NCOL + j0;
            #pragma unroll
            for (int i = 0; i < 5; ++i) orow[i] = xc[i];
        }
    }
}

extern "C" void kernel_launch(void* const* d_in, const int* in_sizes, int n_in,
                              void* d_out, int out_size, void* d_ws, size_t ws_size,
                              hipStream_t stream) {
    const float* b     = (const float*)d_in[0];
    // d_in[1] = target (unused, shape only)
    const float* x0    = (const float*)d_in[2];
    const float* A     = (const float*)d_in[3];
    const float* alpha = (const float*)d_in[4];
    const float* gamma = (const float*)d_in[5];
    const float* lam   = (const float*)d_in[6];
    float* out = (float*)d_out;
    float* ws  = (float*)d_ws;

    ladmm_pre_g<<<dim3((MDIM*NCOL + 255)/256), dim3(256), 0, stream>>>(A, alpha, gamma, ws);
    ladmm_pre_w<<<dim3(1), dim3(256), 0, stream>>>(A, alpha, gamma, ws);
    ladmm_main<<<dim3(NBLOCKS_MAIN), dim3(BLOCK), 0, stream>>>(b, x0, alpha, gamma, lam, ws, out);
}